// Round 5
// baseline (230.062 us; speedup 1.0000x reference)
//
#include <hip/hip_runtime.h>
#include <math.h>

#define HH 128
#define WW 128
#define CC 64
#define BB 8
#define OC 64
#define OFFC 18
#define HW (HH*WW)
#define HP 136
#define WP 136
#define PHW (HP*WP)   /* 18496 */

typedef __attribute__((ext_vector_type(8))) _Float16 f16x8;
typedef __attribute__((ext_vector_type(4))) float f32x4;

// ws layout (floats):
//   P16:    8 img * 8 groups * PHW uint4 (8 fp16 ch each) = BB*32*PHW floats
//   offs:   (retained in layout, now unused)
//   wA_reg: 36864 fp16 (18432 fl) A-frag [(tap*2+kk)*64+o][quad][8j]
//   wA_off: 18432 fp16 (9216 fl)  [(tap*2+kk)*32+o][quad][8j], rows 18..31 zero
#define P_OFF      0
#define P_SIZE     (BB*32*PHW)
#define OFFS_OFF   (P_OFF + P_SIZE)
#define OFFS_SIZE  (BB*OFFC*HW)
#define WAREG_OFF  (OFFS_OFF + OFFS_SIZE)
#define WAREG_SIZE 18432
#define WAOFF_OFF  (WAREG_OFF + WAREG_SIZE)

#define PAD_BLOCKS 4624   /* BB*8*PHW / 256 */
#define PREP_BLOCKS 144

__device__ __forceinline__ unsigned short f2h(float f) {
    _Float16 t = (_Float16)f;
    unsigned short s;
    __builtin_memcpy(&s, &t, 2);
    return s;
}
__device__ __forceinline__ f16x8 u4_to_h8(uint4 u) {
    union { uint4 u; f16x8 h; } c; c.u = u; return c.h;
}
__device__ __forceinline__ uint4 h8_to_u4(f16x8 h) {
    union { uint4 u; f16x8 h; } c; c.h = h; return c.u;
}
__device__ __forceinline__ f16x8 splat8(float f) {
    _Float16 t = (_Float16)f;
    return (f16x8){t, t, t, t, t, t, t, t};
}

// merged prep (weight repack) + pad (fp16 zero-padded P) — one launch.
__global__ __launch_bounds__(256) void prep_pad_kernel(
    const float* __restrict__ x, uint4* __restrict__ P,
    const float* __restrict__ w_reg, const float* __restrict__ w_off,
    unsigned short* __restrict__ wA_reg, unsigned short* __restrict__ wA_off)
{
    int bid = blockIdx.x;
    int tid = threadIdx.x;
    if (bid < PAD_BLOCKS) {
        int idx = bid * 256 + tid;                // over BB*8*PHW
        int pos = idx % PHW;
        int ig  = idx / PHW;                      // img*8 + g
        int r   = pos / WP;
        int col = pos % WP;
        union { uint4 u; f16x8 h; } cv;
        cv.u = make_uint4(0u, 0u, 0u, 0u);
        if (r >= 4 && r <= 131 && col >= 4 && col <= 131) {
            const float* src = x + (ig * 8) * HW + (r - 4) * WW + (col - 4);
            #pragma unroll
            for (int e = 0; e < 8; ++e)
                cv.h[e] = (_Float16)src[e * HW];
        }
        P[idx] = cv.u;
    } else {
        int i = (bid - PAD_BLOCKS) * 256 + tid;
        if (i < 18 * 64 * 32) {
            int j = i & 7, quad = (i >> 3) & 3, o = (i >> 5) & 63, ks = i >> 11;
            int kt = ks >> 1, kk = ks & 1;
            int c = kk * 32 + quad * 8 + j;
            wA_reg[i] = f2h(w_reg[o * 576 + c * 9 + kt]);
        }
        if (i < 18 * 32 * 32) {
            int j = i & 7, quad = (i >> 3) & 3, o = (i >> 5) & 31, ks = i >> 10;
            int kt = ks >> 1, kk = ks & 1;
            int c = kk * 32 + quad * 8 + j;
            float v = (o < OFFC) ? w_off[(o * CC + c) * 9 + kt] : 0.0f;
            wA_off[i] = f2h(v);
        }
    }
}

struct Gather8 {
    uint4 a00, a01, a10, a11;   // group qp*2
    uint4 b00, b01, b10, b11;   // group qp*2+1
    float wx1, wy1;
};

__device__ __forceinline__ Gather8 issue_tap(
    const uint4* __restrict__ xq0, const uint4* __restrict__ xq1,
    int wv, int hv, int dx, int dy, float offx, float offy)
{
    const float scale = 129.0f / 127.0f;
    float pxf = ((float)wv + (float)dx) + offx;
    float pyf = ((float)hv + (float)dy) + offy;
    float qx = fminf(fmaxf(pxf * scale, -100.0f), 300.0f);
    float qy = fminf(fmaxf(pyf * scale, -100.0f), 300.0f);
    float x0f = floorf(qx), y0f = floorf(qy);
    Gather8 g;
    g.wx1 = qx - x0f;
    g.wy1 = qy - y0f;
    int ix0 = (int)x0f, iy0 = (int)y0f;
    int c0 = min(max(ix0 + 3, 0), WP - 2);
    int r0 = min(max(iy0 + 3, 0), HP - 1);
    int r1 = min(max(iy0 + 4, 0), HP - 1);
    int pr0 = r0 * WP + c0, pr1 = r1 * WP + c0;
    g.a00 = xq0[pr0]; g.a01 = xq0[pr0 + 1];
    g.a10 = xq0[pr1]; g.a11 = xq0[pr1 + 1];
    g.b00 = xq1[pr0]; g.b01 = xq1[pr0 + 1];
    g.b10 = xq1[pr1]; g.b11 = xq1[pr1 + 1];
    return g;
}

__device__ __forceinline__ void blend_write(
    uint4* __restrict__ dst, int qp, int pxl, const Gather8& g)
{
    f16x8 wx1v = splat8(g.wx1), wx0v = splat8(1.0f - g.wx1);
    f16x8 wy1v = splat8(g.wy1), wy0v = splat8(1.0f - g.wy1);
    f16x8 r0a = u4_to_h8(g.a00) * wx0v + u4_to_h8(g.a01) * wx1v;
    f16x8 r1a = u4_to_h8(g.a10) * wx0v + u4_to_h8(g.a11) * wx1v;
    dst[(qp * 2 + 0) * 64 + pxl] = h8_to_u4(r0a * wy0v + r1a * wy1v);
    f16x8 r0b = u4_to_h8(g.b00) * wx0v + u4_to_h8(g.b01) * wx1v;
    f16x8 r1b = u4_to_h8(g.b10) * wx0v + u4_to_h8(g.b11) * wx1v;
    dst[(qp * 2 + 1) * 64 + pxl] = h8_to_u4(r0b * wy0v + r1b * wy1v);
}

// Fused, occupancy-optimized: LDS 17.3 KB (conv staged in 2 group-halves into a
// 12.7 KB buffer reused as the 8 KB single xs buffer; offs 4.6 KB) -> 8 blocks/CU
// = 32 waves/CU (was 16). Two raw barriers per tap (write-visible / reads-done).
__global__ __launch_bounds__(256, 8) void fused_deform_kernel(
    const uint4* __restrict__ P, const unsigned short* __restrict__ wA_off,
    const float* __restrict__ b_off, const unsigned short* __restrict__ wA_reg,
    const float* __restrict__ b_reg, float* __restrict__ out)
{
    __shared__ uint4 stage[3 * 4 * 66];        // 12672 B; reused as xs[512] (8 KB)
    __shared__ float offs_lds[OFFC * 64];      // 4608 B
    int img  = blockIdx.x & 7;
    int rest = blockIdx.x >> 3;                // 0..255
    int half = rest & 1;
    int pblk = rest >> 1;                      // row 0..127
    int tid  = threadIdx.x;
    int pxl  = tid & 63;                       // local px
    int qp   = tid >> 6;                       // group pair 0..3
    int lane = tid & 63;
    int wvid = tid >> 6;
    int wv = half * 64 + pxl;
    int hv = pblk;

    // ---- phase 1+2: offset conv in two group-half passes (kk = K-half)
    // output px wv needs P cols wv+dx+3 (dx 0..2) -> base col half*64 + 3
    {
        int s2  = wvid & 1;                    // o-strip
        int ph2 = wvid >> 1;                   // 32-px half
        const f16x8* wOv = (const f16x8*)wA_off;
        f32x4 oacc[2];
        oacc[0] = (f32x4){0.f, 0.f, 0.f, 0.f};
        oacc[1] = (f32x4){0.f, 0.f, 0.f, 0.f};
        for (int kk = 0; kk < 2; ++kk) {
            for (int i = tid; i < 3 * 4 * 66; i += 256) {
                int r   = i / 264;
                int rem = i - r * 264;
                int gl  = rem / 66;
                int j   = rem - gl * 66;
                stage[(r * 4 + gl) * 66 + j] =
                    P[(img * 8 + kk * 4 + gl) * PHW + (pblk + 3 + r) * WP + (half * 64 + 3 + j)];
            }
            __syncthreads();
            const f16x8* xsc = (const f16x8*)stage;
            for (int tap = 0; tap < 9; ++tap) {
                int dy = tap / 3, dx = tap % 3;
                f16x8 a = wOv[((tap * 2 + kk) * 32 + s2 * 16 + (lane & 15)) * 4 + (lane >> 4)];
                #pragma unroll
                for (int pt = 0; pt < 2; ++pt) {
                    int sj = ph2 * 32 + pt * 16 + (lane & 15) + dx;
                    f16x8 b = xsc[(dy * 4 + (lane >> 4)) * 66 + sj];
                    oacc[pt] = __builtin_amdgcn_mfma_f32_16x16x32_f16(a, b, oacc[pt], 0, 0, 0);
                }
            }
            __syncthreads();   // reads done before restage / xs reuse
        }
        #pragma unroll
        for (int r = 0; r < 4; ++r) {
            int o = s2 * 16 + (lane >> 4) * 4 + r;
            if (o < OFFC) {
                float bias = b_off[o];
                #pragma unroll
                for (int pt = 0; pt < 2; ++pt) {
                    int p = ph2 * 32 + pt * 16 + (lane & 15);
                    offs_lds[o * 64 + p] = oacc[pt][r] + bias;
                }
            }
        }
    }
    __syncthreads();   // offs_lds ready

    // ---- phase 3: pipelined deform main loop (single 8 KB xs buffer)
    uint4* xs = stage;
    const f16x8* wAv = (const f16x8*)wA_reg;
    const uint4* xq0 = P + (img * 8 + qp * 2 + 0) * PHW;
    const uint4* xq1 = P + (img * 8 + qp * 2 + 1) * PHW;
    int aidx = (wvid * 16 + (lane & 15)) * 4 + (lane >> 4);

    f32x4 acc[4];
    #pragma unroll
    for (int pt = 0; pt < 4; ++pt) acc[pt] = (f32x4){0.f, 0.f, 0.f, 0.f};

    float ox = offs_lds[0 * 64 + pxl], oy = offs_lds[1 * 64 + pxl];
    Gather8 cur = issue_tap(xq0, xq1, wv, hv, -1, -1, ox, oy);

    #pragma unroll
    for (int tap = 0; tap < 9; ++tap) {
        // 1. blend current corners (vmcnt wait auto-inserted at use), write LDS
        blend_write(xs, qp, pxl, cur);

        // 2. this tap's A-frags (latency hides under barrier + ds_reads)
        f16x8 a0c = wAv[(tap * 2 + 0) * 256 + aidx];
        f16x8 a1c = wAv[(tap * 2 + 1) * 256 + aidx];

        // 3. issue next tap's gathers (stay in flight across both barriers)
        Gather8 nxt;
        if (tap < 8) {
            int dx1 = (tap + 1) % 3 - 1, dy1 = (tap + 1) / 3 - 1;
            float oxn = offs_lds[(2 * tap + 2) * 64 + pxl];
            float oyn = offs_lds[(2 * tap + 3) * 64 + pxl];
            nxt = issue_tap(xq0, xq1, wv, hv, dx1, dy1, oxn, oyn);
        }

        // 4. barrier A: LDS writes visible; prefetched global loads survive
        asm volatile("s_waitcnt lgkmcnt(0)" ::: "memory");
        __builtin_amdgcn_s_barrier();
        asm volatile("" ::: "memory");

        // 5. consume this tap's LDS tile: 16 MFMAs
        const f16x8* xsv = (const f16x8*)xs;
        #pragma unroll
        for (int pt = 0; pt < 4; ++pt) {
            int pxi = pt * 16 + (lane & 15);
            f16x8 b0 = xsv[(lane >> 4) * 64 + pxi];
            acc[pt] = __builtin_amdgcn_mfma_f32_16x16x32_f16(a0c, b0, acc[pt], 0, 0, 0);
            f16x8 b1 = xsv[(4 + (lane >> 4)) * 64 + pxi];
            acc[pt] = __builtin_amdgcn_mfma_f32_16x16x32_f16(a1c, b1, acc[pt], 0, 0, 0);
        }

        // 6. barrier B: all reads consumed before next tap overwrites xs
        asm volatile("s_waitcnt lgkmcnt(0)" ::: "memory");
        __builtin_amdgcn_s_barrier();
        asm volatile("" ::: "memory");

        // 7. rotate pipeline registers (SSA — fully unrolled)
        if (tap < 8) cur = nxt;
    }

    float* op = out + img * (OC * HW) + hv * WW + half * 64;
    #pragma unroll
    for (int r = 0; r < 4; ++r) {
        int o = wvid * 16 + (lane >> 4) * 4 + r;
        float bias = b_reg[o];
        #pragma unroll
        for (int pt = 0; pt < 4; ++pt)
            op[o * HW + pt * 16 + (lane & 15)] = acc[pt][r] + bias;
    }
}

extern "C" void kernel_launch(void* const* d_in, const int* in_sizes, int n_in,
                              void* d_out, int out_size, void* d_ws, size_t ws_size,
                              hipStream_t stream) {
    const float* x     = (const float*)d_in[0];
    const float* w_off = (const float*)d_in[1];
    const float* b_off = (const float*)d_in[2];
    const float* w_reg = (const float*)d_in[3];
    const float* b_reg = (const float*)d_in[4];
    float* out = (float*)d_out;
    float* ws  = (float*)d_ws;

    uint4* P      = (uint4*)(ws + P_OFF);
    unsigned short* wA_reg = (unsigned short*)(ws + WAREG_OFF);
    unsigned short* wA_off = (unsigned short*)(ws + WAOFF_OFF);

    prep_pad_kernel<<<PAD_BLOCKS + PREP_BLOCKS, 256, 0, stream>>>(
        x, P, w_reg, w_off, wA_reg, wA_off);
    fused_deform_kernel<<<2048, 256, 0, stream>>>(
        P, wA_off, b_off, wA_reg, b_reg, out);
}

// Round 7
// 225.583 us; speedup vs baseline: 1.0199x; 1.0199x over previous
//
#include <hip/hip_runtime.h>
#include <math.h>

#define HH 128
#define WW 128
#define CC 64
#define BB 8
#define OC 64
#define OFFC 18
#define HW (HH*WW)
#define HP 136
#define WP 136
#define PHW (HP*WP)   /* 18496 */

typedef __attribute__((ext_vector_type(8))) _Float16 f16x8;
typedef __attribute__((ext_vector_type(4))) float f32x4;

// ws layout (floats):
//   P16:    8 img * 8 groups * PHW uint4 (8 fp16 ch each) = BB*32*PHW floats
//   offs:   (retained in layout, now unused)
//   wA_reg: 36864 fp16 (18432 fl) A-frag [(tap*2+kk)*64+o][quad][8j]
//   wA_off: 18432 fp16 (9216 fl)  [(tap*2+kk)*32+o][quad][8j], rows 18..31 zero
#define P_OFF      0
#define P_SIZE     (BB*32*PHW)
#define OFFS_OFF   (P_OFF + P_SIZE)
#define OFFS_SIZE  (BB*OFFC*HW)
#define WAREG_OFF  (OFFS_OFF + OFFS_SIZE)
#define WAREG_SIZE 18432
#define WAOFF_OFF  (WAREG_OFF + WAREG_SIZE)

#define PAD_BLOCKS 4624   /* BB*8*PHW / 256 */
#define PREP_BLOCKS 144

__device__ __forceinline__ unsigned short f2h(float f) {
    _Float16 t = (_Float16)f;
    unsigned short s;
    __builtin_memcpy(&s, &t, 2);
    return s;
}
__device__ __forceinline__ f16x8 u4_to_h8(uint4 u) {
    union { uint4 u; f16x8 h; } c; c.u = u; return c.h;
}
__device__ __forceinline__ uint4 h8_to_u4(f16x8 h) {
    union { uint4 u; f16x8 h; } c; c.h = h; return c.u;
}
__device__ __forceinline__ f16x8 splat8(float f) {
    _Float16 t = (_Float16)f;
    return (f16x8){t, t, t, t, t, t, t, t};
}

// merged prep (weight repack) + pad (fp16 zero-padded P) — one launch.
__global__ __launch_bounds__(256) void prep_pad_kernel(
    const float* __restrict__ x, uint4* __restrict__ P,
    const float* __restrict__ w_reg, const float* __restrict__ w_off,
    unsigned short* __restrict__ wA_reg, unsigned short* __restrict__ wA_off)
{
    int bid = blockIdx.x;
    int tid = threadIdx.x;
    if (bid < PAD_BLOCKS) {
        int idx = bid * 256 + tid;                // over BB*8*PHW
        int pos = idx % PHW;
        int ig  = idx / PHW;                      // img*8 + g
        int r   = pos / WP;
        int col = pos % WP;
        union { uint4 u; f16x8 h; } cv;
        cv.u = make_uint4(0u, 0u, 0u, 0u);
        if (r >= 4 && r <= 131 && col >= 4 && col <= 131) {
            const float* src = x + (ig * 8) * HW + (r - 4) * WW + (col - 4);
            #pragma unroll
            for (int e = 0; e < 8; ++e)
                cv.h[e] = (_Float16)src[e * HW];
        }
        P[idx] = cv.u;
    } else {
        int i = (bid - PAD_BLOCKS) * 256 + tid;
        if (i < 18 * 64 * 32) {
            int j = i & 7, quad = (i >> 3) & 3, o = (i >> 5) & 63, ks = i >> 11;
            int kt = ks >> 1, kk = ks & 1;
            int c = kk * 32 + quad * 8 + j;
            wA_reg[i] = f2h(w_reg[o * 576 + c * 9 + kt]);
        }
        if (i < 18 * 32 * 32) {
            int j = i & 7, quad = (i >> 3) & 3, o = (i >> 5) & 31, ks = i >> 10;
            int kt = ks >> 1, kk = ks & 1;
            int c = kk * 32 + quad * 8 + j;
            float v = (o < OFFC) ? w_off[(o * CC + c) * 9 + kt] : 0.0f;
            wA_off[i] = f2h(v);
        }
    }
}

struct Gather8 {
    uint4 a00, a01, a10, a11;   // group qp*2
    uint4 b00, b01, b10, b11;   // group qp*2+1
    float wx1, wy1;
};

__device__ __forceinline__ Gather8 issue_tap(
    const uint4* __restrict__ xq0, const uint4* __restrict__ xq1,
    int wv, int hv, int dx, int dy, float offx, float offy)
{
    const float scale = 129.0f / 127.0f;
    float pxf = ((float)wv + (float)dx) + offx;
    float pyf = ((float)hv + (float)dy) + offy;
    float qx = fminf(fmaxf(pxf * scale, -100.0f), 300.0f);
    float qy = fminf(fmaxf(pyf * scale, -100.0f), 300.0f);
    float x0f = floorf(qx), y0f = floorf(qy);
    Gather8 g;
    g.wx1 = qx - x0f;
    g.wy1 = qy - y0f;
    int ix0 = (int)x0f, iy0 = (int)y0f;
    int c0 = min(max(ix0 + 3, 0), WP - 2);
    int r0 = min(max(iy0 + 3, 0), HP - 1);
    int r1 = min(max(iy0 + 4, 0), HP - 1);
    int pr0 = r0 * WP + c0, pr1 = r1 * WP + c0;
    g.a00 = xq0[pr0]; g.a01 = xq0[pr0 + 1];
    g.a10 = xq0[pr1]; g.a11 = xq0[pr1 + 1];
    g.b00 = xq1[pr0]; g.b01 = xq1[pr0 + 1];
    g.b10 = xq1[pr1]; g.b11 = xq1[pr1 + 1];
    return g;
}

__device__ __forceinline__ void blend_write(
    uint4* __restrict__ dst, int qp, int pxl, const Gather8& g)
{
    f16x8 wx1v = splat8(g.wx1), wx0v = splat8(1.0f - g.wx1);
    f16x8 wy1v = splat8(g.wy1), wy0v = splat8(1.0f - g.wy1);
    f16x8 r0a = u4_to_h8(g.a00) * wx0v + u4_to_h8(g.a01) * wx1v;
    f16x8 r1a = u4_to_h8(g.a10) * wx0v + u4_to_h8(g.a11) * wx1v;
    dst[(qp * 2 + 0) * 64 + pxl] = h8_to_u4(r0a * wy0v + r1a * wy1v);
    f16x8 r0b = u4_to_h8(g.b00) * wx0v + u4_to_h8(g.b01) * wx1v;
    f16x8 r1b = u4_to_h8(g.b10) * wx0v + u4_to_h8(g.b11) * wx1v;
    dst[(qp * 2 + 1) * 64 + pxl] = h8_to_u4(r0b * wy0v + r1b * wy1v);
}

// Fused. LDS = 16 KB shbuf (conv stage 12.7 KB, then 2x8 KB xs ping-pong)
// + 4.6 KB offs = 21 KB -> 7 blocks/CU. launch_bounds(256,7) caps VGPR at 73:
// above the ~60-VGPR live set (NO spill — round-5's (256,8)=64 cap spilled
// 350 MB of scratch traffic), below round-4's 128 (which allowed only 4 blocks).
__global__ __launch_bounds__(256, 7) void fused_deform_kernel(
    const uint4* __restrict__ P, const unsigned short* __restrict__ wA_off,
    const float* __restrict__ b_off, const unsigned short* __restrict__ wA_reg,
    const float* __restrict__ b_reg, float* __restrict__ out)
{
    __shared__ uint4 shbuf[1024];              // 16384 B
    __shared__ float offs_lds[OFFC * 64];      // 4608 B
    int img  = blockIdx.x & 7;
    int rest = blockIdx.x >> 3;                // 0..255
    int half = rest & 1;
    int pblk = rest >> 1;                      // row 0..127
    int tid  = threadIdx.x;
    int pxl  = tid & 63;                       // local px
    int qp   = tid >> 6;                       // group pair 0..3
    int lane = tid & 63;
    int wvid = tid >> 6;
    int wv = half * 64 + pxl;
    int hv = pblk;

    // ---- phase 1+2: offset conv in two group-half passes (kk = K-half)
    // output px wv needs P cols wv+dx+3 (dx 0..2) -> base col half*64 + 3
    {
        int s2  = wvid & 1;                    // o-strip
        int ph2 = wvid >> 1;                   // 32-px half
        const f16x8* wOv = (const f16x8*)wA_off;
        f32x4 oacc[2];
        oacc[0] = (f32x4){0.f, 0.f, 0.f, 0.f};
        oacc[1] = (f32x4){0.f, 0.f, 0.f, 0.f};
        for (int kk = 0; kk < 2; ++kk) {
            for (int i = tid; i < 3 * 4 * 66; i += 256) {
                int r   = i / 264;
                int rem = i - r * 264;
                int gl  = rem / 66;
                int j   = rem - gl * 66;
                shbuf[(r * 4 + gl) * 66 + j] =
                    P[(img * 8 + kk * 4 + gl) * PHW + (pblk + 3 + r) * WP + (half * 64 + 3 + j)];
            }
            __syncthreads();
            const f16x8* xsc = (const f16x8*)shbuf;
            for (int tap = 0; tap < 9; ++tap) {
                int dy = tap / 3, dx = tap % 3;
                f16x8 a = wOv[((tap * 2 + kk) * 32 + s2 * 16 + (lane & 15)) * 4 + (lane >> 4)];
                #pragma unroll
                for (int pt = 0; pt < 2; ++pt) {
                    int sj = ph2 * 32 + pt * 16 + (lane & 15) + dx;
                    f16x8 b = xsc[(dy * 4 + (lane >> 4)) * 66 + sj];
                    oacc[pt] = __builtin_amdgcn_mfma_f32_16x16x32_f16(a, b, oacc[pt], 0, 0, 0);
                }
            }
            __syncthreads();   // reads done before restage / xs reuse
        }
        #pragma unroll
        for (int r = 0; r < 4; ++r) {
            int o = s2 * 16 + (lane >> 4) * 4 + r;
            if (o < OFFC) {
                float bias = b_off[o];
                #pragma unroll
                for (int pt = 0; pt < 2; ++pt) {
                    int p = ph2 * 32 + pt * 16 + (lane & 15);
                    offs_lds[o * 64 + p] = oacc[pt][r] + bias;
                }
            }
        }
    }
    __syncthreads();   // offs_lds ready; shbuf reusable as xs ping-pong

    // ---- phase 3: pipelined deform main loop (2x8 KB ping-pong in shbuf)
    const f16x8* wAv = (const f16x8*)wA_reg;
    const uint4* xq0 = P + (img * 8 + qp * 2 + 0) * PHW;
    const uint4* xq1 = P + (img * 8 + qp * 2 + 1) * PHW;
    int aidx = (wvid * 16 + (lane & 15)) * 4 + (lane >> 4);

    f32x4 acc[4];
    #pragma unroll
    for (int pt = 0; pt < 4; ++pt) acc[pt] = (f32x4){0.f, 0.f, 0.f, 0.f};

    float ox = offs_lds[0 * 64 + pxl], oy = offs_lds[1 * 64 + pxl];
    Gather8 cur = issue_tap(xq0, xq1, wv, hv, -1, -1, ox, oy);
    f16x8 a0c = wAv[0 * 256 + aidx];
    f16x8 a1c = wAv[1 * 256 + aidx];

    #pragma unroll
    for (int tap = 0; tap < 9; ++tap) {
        // 1. blend current corners (vmcnt wait auto-inserted at use), write LDS
        uint4* dst = shbuf + (tap & 1) * 512;
        blend_write(dst, qp, pxl, cur);

        // 2. issue next tap's gathers + A-frags (stay in flight across barrier)
        Gather8 nxt;
        f16x8 a0n, a1n;
        if (tap < 8) {
            int dx1 = (tap + 1) % 3 - 1, dy1 = (tap + 1) / 3 - 1;
            float oxn = offs_lds[(2 * tap + 2) * 64 + pxl];
            float oyn = offs_lds[(2 * tap + 3) * 64 + pxl];
            nxt = issue_tap(xq0, xq1, wv, hv, dx1, dy1, oxn, oyn);
            a0n = wAv[((tap + 1) * 2 + 0) * 256 + aidx];
            a1n = wAv[((tap + 1) * 2 + 1) * 256 + aidx];
        }

        // 3. barrier: drain LDS ops only — in-flight global loads survive
        asm volatile("s_waitcnt lgkmcnt(0)" ::: "memory");
        __builtin_amdgcn_s_barrier();
        asm volatile("" ::: "memory");

        // 4. consume this tap's LDS tile: 16 MFMAs
        const f16x8* xsv = (const f16x8*)(shbuf + (tap & 1) * 512);
        #pragma unroll
        for (int pt = 0; pt < 4; ++pt) {
            int pxi = pt * 16 + (lane & 15);
            f16x8 b0 = xsv[(lane >> 4) * 64 + pxi];
            acc[pt] = __builtin_amdgcn_mfma_f32_16x16x32_f16(a0c, b0, acc[pt], 0, 0, 0);
            f16x8 b1 = xsv[(4 + (lane >> 4)) * 64 + pxi];
            acc[pt] = __builtin_amdgcn_mfma_f32_16x16x32_f16(a1c, b1, acc[pt], 0, 0, 0);
        }

        // 5. rotate pipeline registers (SSA — fully unrolled)
        if (tap < 8) {
            cur = nxt; a0c = a0n; a1c = a1n;
        }
    }

    float* op = out + img * (OC * HW) + hv * WW + half * 64;
    #pragma unroll
    for (int r = 0; r < 4; ++r) {
        int o = wvid * 16 + (lane >> 4) * 4 + r;
        float bias = b_reg[o];
        #pragma unroll
        for (int pt = 0; pt < 4; ++pt)
            op[o * HW + pt * 16 + (lane & 15)] = acc[pt][r] + bias;
    }
}

extern "C" void kernel_launch(void* const* d_in, const int* in_sizes, int n_in,
                              void* d_out, int out_size, void* d_ws, size_t ws_size,
                              hipStream_t stream) {
    const float* x     = (const float*)d_in[0];
    const float* w_off = (const float*)d_in[1];
    const float* b_off = (const float*)d_in[2];
    const float* w_reg = (const float*)d_in[3];
    const float* b_reg = (const float*)d_in[4];
    float* out = (float*)d_out;
    float* ws  = (float*)d_ws;

    uint4* P      = (uint4*)(ws + P_OFF);
    unsigned short* wA_reg = (unsigned short*)(ws + WAREG_OFF);
    unsigned short* wA_off = (unsigned short*)(ws + WAOFF_OFF);

    prep_pad_kernel<<<PAD_BLOCKS + PREP_BLOCKS, 256, 0, stream>>>(
        x, P, w_reg, w_off, wA_reg, wA_off);
    fused_deform_kernel<<<2048, 256, 0, stream>>>(
        P, wA_off, b_off, wA_reg, b_reg, out);
}

// Round 8
// 179.409 us; speedup vs baseline: 1.2823x; 1.2574x over previous
//
#include <hip/hip_runtime.h>
#include <math.h>

#define HH 128
#define WW 128
#define CC 64
#define BB 8
#define OC 64
#define OFFC 18
#define HW (HH*WW)
#define HP 136
#define WP 136
#define PHW (HP*WP)   /* 18496 */

typedef __attribute__((ext_vector_type(8))) _Float16 f16x8;
typedef __attribute__((ext_vector_type(4))) float f32x4;

// ws layout (floats):
//   P16:    8 img * 8 groups * PHW uint4 (8 fp16 ch each) = BB*32*PHW floats
//   offs:   (retained in layout, now unused)
//   wA_reg: 36864 fp16 (18432 fl) A-frag [(tap*2+kk)*64+o][quad][8j]
//   wA_off: 18432 fp16 (9216 fl)  [(tap*2+kk)*32+o][quad][8j], rows 18..31 zero
#define P_OFF      0
#define P_SIZE     (BB*32*PHW)
#define OFFS_OFF   (P_OFF + P_SIZE)
#define OFFS_SIZE  (BB*OFFC*HW)
#define WAREG_OFF  (OFFS_OFF + OFFS_SIZE)
#define WAREG_SIZE 18432
#define WAOFF_OFF  (WAREG_OFF + WAREG_SIZE)

#define PAD_BLOCKS 4624   /* BB*8*PHW / 256 */
#define PREP_BLOCKS 144

__device__ __forceinline__ unsigned short f2h(float f) {
    _Float16 t = (_Float16)f;
    unsigned short s;
    __builtin_memcpy(&s, &t, 2);
    return s;
}
__device__ __forceinline__ f16x8 u4_to_h8(uint4 u) {
    union { uint4 u; f16x8 h; } c; c.u = u; return c.h;
}
__device__ __forceinline__ uint4 h8_to_u4(f16x8 h) {
    union { uint4 u; f16x8 h; } c; c.h = h; return c.u;
}
__device__ __forceinline__ f16x8 splat8(float f) {
    _Float16 t = (_Float16)f;
    return (f16x8){t, t, t, t, t, t, t, t};
}

// merged prep (weight repack) + pad (fp16 zero-padded P) — one launch.
__global__ __launch_bounds__(256) void prep_pad_kernel(
    const float* __restrict__ x, uint4* __restrict__ P,
    const float* __restrict__ w_reg, const float* __restrict__ w_off,
    unsigned short* __restrict__ wA_reg, unsigned short* __restrict__ wA_off)
{
    int bid = blockIdx.x;
    int tid = threadIdx.x;
    if (bid < PAD_BLOCKS) {
        int idx = bid * 256 + tid;                // over BB*8*PHW
        int pos = idx % PHW;
        int ig  = idx / PHW;                      // img*8 + g
        int r   = pos / WP;
        int col = pos % WP;
        union { uint4 u; f16x8 h; } cv;
        cv.u = make_uint4(0u, 0u, 0u, 0u);
        if (r >= 4 && r <= 131 && col >= 4 && col <= 131) {
            const float* src = x + (ig * 8) * HW + (r - 4) * WW + (col - 4);
            #pragma unroll
            for (int e = 0; e < 8; ++e)
                cv.h[e] = (_Float16)src[e * HW];
        }
        P[idx] = cv.u;
    } else {
        int i = (bid - PAD_BLOCKS) * 256 + tid;
        if (i < 18 * 64 * 32) {
            int j = i & 7, quad = (i >> 3) & 3, o = (i >> 5) & 63, ks = i >> 11;
            int kt = ks >> 1, kk = ks & 1;
            int c = kk * 32 + quad * 8 + j;
            wA_reg[i] = f2h(w_reg[o * 576 + c * 9 + kt]);
        }
        if (i < 18 * 32 * 32) {
            int j = i & 7, quad = (i >> 3) & 3, o = (i >> 5) & 31, ks = i >> 10;
            int kt = ks >> 1, kk = ks & 1;
            int c = kk * 32 + quad * 8 + j;
            float v = (o < OFFC) ? w_off[(o * CC + c) * 9 + kt] : 0.0f;
            wA_off[i] = f2h(v);
        }
    }
}

struct Gather8 {
    uint4 a00, a01, a10, a11;   // group qp*2
    uint4 b00, b01, b10, b11;   // group qp*2+1
    float wx1, wy1;
};

__device__ __forceinline__ Gather8 issue_tap(
    const uint4* __restrict__ xq0, const uint4* __restrict__ xq1,
    int wv, int hv, int dx, int dy, float offx, float offy)
{
    const float scale = 129.0f / 127.0f;
    float pxf = ((float)wv + (float)dx) + offx;
    float pyf = ((float)hv + (float)dy) + offy;
    float qx = fminf(fmaxf(pxf * scale, -100.0f), 300.0f);
    float qy = fminf(fmaxf(pyf * scale, -100.0f), 300.0f);
    float x0f = floorf(qx), y0f = floorf(qy);
    Gather8 g;
    g.wx1 = qx - x0f;
    g.wy1 = qy - y0f;
    int ix0 = (int)x0f, iy0 = (int)y0f;
    int c0 = min(max(ix0 + 3, 0), WP - 2);
    int r0 = min(max(iy0 + 3, 0), HP - 1);
    int r1 = min(max(iy0 + 4, 0), HP - 1);
    int pr0 = r0 * WP + c0, pr1 = r1 * WP + c0;
    g.a00 = xq0[pr0]; g.a01 = xq0[pr0 + 1];
    g.a10 = xq0[pr1]; g.a11 = xq0[pr1 + 1];
    g.b00 = xq1[pr0]; g.b01 = xq1[pr0 + 1];
    g.b10 = xq1[pr1]; g.b11 = xq1[pr1 + 1];
    return g;
}

__device__ __forceinline__ void blend_write(
    uint4* __restrict__ dst, int qp, int pxl, const Gather8& g)
{
    f16x8 wx1v = splat8(g.wx1), wx0v = splat8(1.0f - g.wx1);
    f16x8 wy1v = splat8(g.wy1), wy0v = splat8(1.0f - g.wy1);
    f16x8 r0a = u4_to_h8(g.a00) * wx0v + u4_to_h8(g.a01) * wx1v;
    f16x8 r1a = u4_to_h8(g.a10) * wx0v + u4_to_h8(g.a11) * wx1v;
    dst[(qp * 2 + 0) * 64 + pxl] = h8_to_u4(r0a * wy0v + r1a * wy1v);
    f16x8 r0b = u4_to_h8(g.b00) * wx0v + u4_to_h8(g.b01) * wx1v;
    f16x8 r1b = u4_to_h8(g.b10) * wx0v + u4_to_h8(g.b11) * wx1v;
    dst[(qp * 2 + 1) * 64 + pxl] = h8_to_u4(r0b * wy0v + r1b * wy1v);
}

// Fused, NON-pipelined main loop (round-2 A/B showed prefetch-depth-1 is null,
// and its +32 VGPR is what forced the round-5/7 spills). LDS = 16 KB shbuf
// (conv stage 12.7 KB, then 2x8 KB xs ping-pong) + 4.6 KB offs = 21 KB ->
// 7 blocks/CU; launch_bounds(256,7) with the ~60-VGPR non-pipelined live set.
__global__ __launch_bounds__(256, 7) void fused_deform_kernel(
    const uint4* __restrict__ P, const unsigned short* __restrict__ wA_off,
    const float* __restrict__ b_off, const unsigned short* __restrict__ wA_reg,
    const float* __restrict__ b_reg, float* __restrict__ out)
{
    __shared__ uint4 shbuf[1024];              // 16384 B
    __shared__ float offs_lds[OFFC * 64];      // 4608 B
    int img  = blockIdx.x & 7;
    int rest = blockIdx.x >> 3;                // 0..255
    int half = rest & 1;
    int pblk = rest >> 1;                      // row 0..127
    int tid  = threadIdx.x;
    int pxl  = tid & 63;                       // local px
    int qp   = tid >> 6;                       // group pair 0..3
    int lane = tid & 63;
    int wvid = tid >> 6;
    int wv = half * 64 + pxl;
    int hv = pblk;

    // ---- phase 1+2: offset conv in two group-half passes (kk = K-half)
    // output px wv needs P cols wv+dx+3 (dx 0..2) -> base col half*64 + 3
    {
        int s2  = wvid & 1;                    // o-strip
        int ph2 = wvid >> 1;                   // 32-px half
        const f16x8* wOv = (const f16x8*)wA_off;
        f32x4 oacc[2];
        oacc[0] = (f32x4){0.f, 0.f, 0.f, 0.f};
        oacc[1] = (f32x4){0.f, 0.f, 0.f, 0.f};
        for (int kk = 0; kk < 2; ++kk) {
            for (int i = tid; i < 3 * 4 * 66; i += 256) {
                int r   = i / 264;
                int rem = i - r * 264;
                int gl  = rem / 66;
                int j   = rem - gl * 66;
                shbuf[(r * 4 + gl) * 66 + j] =
                    P[(img * 8 + kk * 4 + gl) * PHW + (pblk + 3 + r) * WP + (half * 64 + 3 + j)];
            }
            __syncthreads();
            const f16x8* xsc = (const f16x8*)shbuf;
            for (int tap = 0; tap < 9; ++tap) {
                int dy = tap / 3, dx = tap % 3;
                f16x8 a = wOv[((tap * 2 + kk) * 32 + s2 * 16 + (lane & 15)) * 4 + (lane >> 4)];
                #pragma unroll
                for (int pt = 0; pt < 2; ++pt) {
                    int sj = ph2 * 32 + pt * 16 + (lane & 15) + dx;
                    f16x8 b = xsc[(dy * 4 + (lane >> 4)) * 66 + sj];
                    oacc[pt] = __builtin_amdgcn_mfma_f32_16x16x32_f16(a, b, oacc[pt], 0, 0, 0);
                }
            }
            __syncthreads();   // reads done before restage / xs reuse
        }
        #pragma unroll
        for (int r = 0; r < 4; ++r) {
            int o = s2 * 16 + (lane >> 4) * 4 + r;
            if (o < OFFC) {
                float bias = b_off[o];
                #pragma unroll
                for (int pt = 0; pt < 2; ++pt) {
                    int p = ph2 * 32 + pt * 16 + (lane & 15);
                    offs_lds[o * 64 + p] = oacc[pt][r] + bias;
                }
            }
        }
    }
    __syncthreads();   // offs_lds ready; shbuf reusable as xs ping-pong

    // ---- phase 3: deform main loop (round-0 verified structure;
    //      ping-pong 2x8 KB in shbuf, ONE __syncthreads per tap)
    const f16x8* wAv = (const f16x8*)wA_reg;
    const uint4* xq0 = P + (img * 8 + qp * 2 + 0) * PHW;
    const uint4* xq1 = P + (img * 8 + qp * 2 + 1) * PHW;
    int aidx = (wvid * 16 + (lane & 15)) * 4 + (lane >> 4);

    f32x4 acc[4];
    #pragma unroll
    for (int pt = 0; pt < 4; ++pt) acc[pt] = (f32x4){0.f, 0.f, 0.f, 0.f};

    for (int tap = 0; tap < 9; ++tap) {
        float ox = offs_lds[(2 * tap + 0) * 64 + pxl];
        float oy = offs_lds[(2 * tap + 1) * 64 + pxl];
        f16x8 a0c = wAv[(tap * 2 + 0) * 256 + aidx];
        f16x8 a1c = wAv[(tap * 2 + 1) * 256 + aidx];

        Gather8 cur = issue_tap(xq0, xq1, wv, hv, tap % 3 - 1, tap / 3 - 1, ox, oy);
        uint4* dst = shbuf + (tap & 1) * 512;
        blend_write(dst, qp, pxl, cur);
        __syncthreads();

        const f16x8* xsv = (const f16x8*)(shbuf + (tap & 1) * 512);
        #pragma unroll
        for (int pt = 0; pt < 4; ++pt) {
            int pxi = pt * 16 + (lane & 15);
            f16x8 b0 = xsv[(lane >> 4) * 64 + pxi];
            acc[pt] = __builtin_amdgcn_mfma_f32_16x16x32_f16(a0c, b0, acc[pt], 0, 0, 0);
            f16x8 b1 = xsv[(4 + (lane >> 4)) * 64 + pxi];
            acc[pt] = __builtin_amdgcn_mfma_f32_16x16x32_f16(a1c, b1, acc[pt], 0, 0, 0);
        }
    }

    float* op = out + img * (OC * HW) + hv * WW + half * 64;
    #pragma unroll
    for (int r = 0; r < 4; ++r) {
        int o = wvid * 16 + (lane >> 4) * 4 + r;
        float bias = b_reg[o];
        #pragma unroll
        for (int pt = 0; pt < 4; ++pt)
            op[o * HW + pt * 16 + (lane & 15)] = acc[pt][r] + bias;
    }
}

extern "C" void kernel_launch(void* const* d_in, const int* in_sizes, int n_in,
                              void* d_out, int out_size, void* d_ws, size_t ws_size,
                              hipStream_t stream) {
    const float* x     = (const float*)d_in[0];
    const float* w_off = (const float*)d_in[1];
    const float* b_off = (const float*)d_in[2];
    const float* w_reg = (const float*)d_in[3];
    const float* b_reg = (const float*)d_in[4];
    float* out = (float*)d_out;
    float* ws  = (float*)d_ws;

    uint4* P      = (uint4*)(ws + P_OFF);
    unsigned short* wA_reg = (unsigned short*)(ws + WAREG_OFF);
    unsigned short* wA_off = (unsigned short*)(ws + WAOFF_OFF);

    prep_pad_kernel<<<PAD_BLOCKS + PREP_BLOCKS, 256, 0, stream>>>(
        x, P, w_reg, w_off, wA_reg, wA_off);
    fused_deform_kernel<<<2048, 256, 0, stream>>>(
        P, wA_off, b_off, wA_reg, b_reg, out);
}